// Round 10
// baseline (21.013 us; speedup 1.0000x reference)
//
#include <hip/hip_runtime.h>

__device__ __forceinline__ float frcp(float x) { return __builtin_amdgcn_rcpf(x); }

#define ROWS 128                    // rows per block (= blockDim.x); 2 waves/block
#define BLK_F4 (ROWS * 10 / 4)      // 320 float4 chunks per block

__global__ __launch_bounds__(128) void amber_dyn_lds(
    const float4* __restrict__ st4,   // state as float4 stream [B*10/4]
    const float4* __restrict__ u4,    // [B]
    float4* __restrict__ out4,        // [B*10/4]
    int B)
{
    __shared__ float lds[ROWS * 10];            // 5120 B
    float4* lds4 = reinterpret_cast<float4*>(lds);

    const int tid = threadIdx.x;
    const int f4base = blockIdx.x * BLK_F4;
    const int totalF4 = B * 10 / 4;

    const int row = blockIdx.x * ROWS + tid;
    // hoist u load: HBM latency overlaps stage 1 + barrier
    float4 uv = (row < B) ? u4[row] : make_float4(0.f, 0.f, 0.f, 0.f);

    // ---- stage 1: coalesced global b128 -> linear LDS ----
    #pragma unroll
    for (int it = 0; it < 3; ++it) {
        int i = tid + it * ROWS;
        if (i < BLK_F4) {
            int g = f4base + i;
            if (g < totalF4) lds4[i] = st4[g];
        }
    }
    __syncthreads();

    // ---- stage 2: per-thread row compute (own row only, in place) ----
    if (row < B) {
        float* myrow = lds + tid * 10;
        float q[5], qd[5];
        #pragma unroll
        for (int i = 0; i < 5; ++i) { q[i] = myrow[i]; qd[i] = myrow[5 + i]; }

        float s[5], c[5];
        #pragma unroll
        for (int i = 0; i < 5; ++i) __sincosf(q[i], &s[i], &c[i]);

        float v2 = qd[0]*qd[0] + qd[1]*qd[1] + qd[2]*qd[2] + qd[3]*qd[3] + qd[4]*qd[4];
        float coef = 0.1f * v2 + 9.8f;

        float bu[5] = {0.f, uv.x, uv.y, uv.z, uv.w};
        float r[5];
        #pragma unroll
        for (int i = 0; i < 5; ++i)
            r[i] = bu[i] - (coef * s[i] + 0.05f * qd[i]);

        // Woodbury: D = 2I + 0.3(cc^T+ss^T);
        // D^-1 r = 0.5 r - 0.25 U M^-1 U^T r,  M = (10/3)I + 0.5 U^T U
        float cc = 0.f, cs = 0.f, pc = 0.f, ps = 0.f;
        #pragma unroll
        for (int i = 0; i < 5; ++i) {
            cc += c[i]*c[i]; cs += c[i]*s[i];
            pc += c[i]*r[i]; ps += s[i]*r[i];
        }
        float ss = 5.0f - cc;                   // ci^2+si^2 = 1

        const float K = 10.0f / 3.0f;
        float m00 = K + 0.5f * cc;
        float m01 = 0.5f * cs;
        float m11 = K + 0.5f * ss;

        float idet = frcp(m00 * m11 - m01 * m01);
        float y0 = 0.25f * idet * (m11 * pc - m01 * ps);
        float y1 = 0.25f * idet * (m00 * ps - m01 * pc);

        #pragma unroll
        for (int i = 0; i < 5; ++i) {
            myrow[i]     = qd[i];
            myrow[5 + i] = 0.5f * r[i] - (c[i] * y0 + s[i] * y1);
        }
    }
    __syncthreads();

    // ---- stage 3: linear LDS -> coalesced global b128 ----
    #pragma unroll
    for (int it = 0; it < 3; ++it) {
        int i = tid + it * ROWS;
        if (i < BLK_F4) {
            int g = f4base + i;
            if (g < totalF4) out4[g] = lds4[i];
        }
    }
}

extern "C" void kernel_launch(void* const* d_in, const int* in_sizes, int n_in,
                              void* d_out, int out_size, void* d_ws, size_t ws_size,
                              hipStream_t stream) {
    // inputs (setup_inputs order): t [1], state [B*10], u [B*4]
    const float* state = (const float*)d_in[1];
    const float* u     = (const float*)d_in[2];
    float* out = (float*)d_out;
    int B = in_sizes[1] / 10;

    int grid = (B + ROWS - 1) / ROWS;
    amber_dyn_lds<<<grid, ROWS, 0, stream>>>(
        (const float4*)state, (const float4*)u, (float4*)out, B);
}

// Round 11
// 20.849 us; speedup vs baseline: 1.0079x; 1.0079x over previous
//
#include <hip/hip_runtime.h>

// R5 configuration — best measured (19.94 us). Every perturbation tested
// regressed: 2-row/thread (+8-10us), row padding (+1.0), nt hints (+0.6),
// wave-sync (+1.1), 128-thr (+1.1), 512-thr (+1.2). Do not "improve".

__device__ __forceinline__ float frcp(float x) { return __builtin_amdgcn_rcpf(x); }

#define ROWS 256                    // rows per block (= blockDim.x)
#define BLK_F4 (ROWS * 10 / 4)      // 640 float4 chunks per block

__global__ __launch_bounds__(256) void amber_dyn_lds(
    const float4* __restrict__ st4,   // state as float4 stream [B*10/4]
    const float4* __restrict__ u4,    // [B]
    float4* __restrict__ out4,        // [B*10/4]
    int B)
{
    __shared__ float lds[ROWS * 10];            // 10240 B
    float4* lds4 = reinterpret_cast<float4*>(lds);

    const int tid = threadIdx.x;
    const int f4base = blockIdx.x * BLK_F4;
    const int totalF4 = B * 10 / 4;

    const int row = blockIdx.x * ROWS + tid;
    // hoist u load: HBM latency overlaps stage 1 + barrier
    float4 uv = (row < B) ? u4[row] : make_float4(0.f, 0.f, 0.f, 0.f);

    // ---- stage 1: coalesced global b128 -> linear LDS ----
    #pragma unroll
    for (int it = 0; it < 3; ++it) {
        int i = tid + it * ROWS;
        if (i < BLK_F4) {
            int g = f4base + i;
            if (g < totalF4) lds4[i] = st4[g];
        }
    }
    __syncthreads();

    // ---- stage 2: per-thread row compute (own row only, in place) ----
    if (row < B) {
        float* myrow = lds + tid * 10;
        float q[5], qd[5];
        #pragma unroll
        for (int i = 0; i < 5; ++i) { q[i] = myrow[i]; qd[i] = myrow[5 + i]; }

        float s[5], c[5];
        #pragma unroll
        for (int i = 0; i < 5; ++i) __sincosf(q[i], &s[i], &c[i]);

        float v2 = qd[0]*qd[0] + qd[1]*qd[1] + qd[2]*qd[2] + qd[3]*qd[3] + qd[4]*qd[4];
        float coef = 0.1f * v2 + 9.8f;

        float bu[5] = {0.f, uv.x, uv.y, uv.z, uv.w};
        float r[5];
        #pragma unroll
        for (int i = 0; i < 5; ++i)
            r[i] = bu[i] - (coef * s[i] + 0.05f * qd[i]);

        // Woodbury: D = 2I + 0.3(cc^T+ss^T);
        // D^-1 r = 0.5 r - 0.25 U M^-1 U^T r,  M = (10/3)I + 0.5 U^T U
        float cc = 0.f, cs = 0.f, pc = 0.f, ps = 0.f;
        #pragma unroll
        for (int i = 0; i < 5; ++i) {
            cc += c[i]*c[i]; cs += c[i]*s[i];
            pc += c[i]*r[i]; ps += s[i]*r[i];
        }
        float ss = 5.0f - cc;                   // ci^2+si^2 = 1

        const float K = 10.0f / 3.0f;
        float m00 = K + 0.5f * cc;
        float m01 = 0.5f * cs;
        float m11 = K + 0.5f * ss;

        float idet = frcp(m00 * m11 - m01 * m01);
        float y0 = 0.25f * idet * (m11 * pc - m01 * ps);
        float y1 = 0.25f * idet * (m00 * ps - m01 * pc);

        #pragma unroll
        for (int i = 0; i < 5; ++i) {
            myrow[i]     = qd[i];
            myrow[5 + i] = 0.5f * r[i] - (c[i] * y0 + s[i] * y1);
        }
    }
    __syncthreads();

    // ---- stage 3: linear LDS -> coalesced global b128 ----
    #pragma unroll
    for (int it = 0; it < 3; ++it) {
        int i = tid + it * ROWS;
        if (i < BLK_F4) {
            int g = f4base + i;
            if (g < totalF4) out4[g] = lds4[i];
        }
    }
}

extern "C" void kernel_launch(void* const* d_in, const int* in_sizes, int n_in,
                              void* d_out, int out_size, void* d_ws, size_t ws_size,
                              hipStream_t stream) {
    // inputs (setup_inputs order): t [1], state [B*10], u [B*4]
    const float* state = (const float*)d_in[1];
    const float* u     = (const float*)d_in[2];
    float* out = (float*)d_out;
    int B = in_sizes[1] / 10;

    int grid = (B + ROWS - 1) / ROWS;
    amber_dyn_lds<<<grid, ROWS, 0, stream>>>(
        (const float4*)state, (const float4*)u, (float4*)out, B);
}